// Round 1
// baseline (333.132 us; speedup 1.0000x reference)
//
#include <hip/hip_runtime.h>
#include <hip/hip_bf16.h>
#include <math.h>

#define M_SAMPLES_MAX 8192
#define E_DIM 128
#define R_DIM 128
#define REG_LAMBDA 1e-5f

// One block (128 threads) per sample m.
// Thread t owns output column t of the 128-wide matvec results.
__global__ void __launch_bounds__(128)
kge_sample_kernel(const int* __restrict__ h_idx, const int* __restrict__ r_idx,
                  const int* __restrict__ pt_idx, const int* __restrict__ nt_idx,
                  const float* __restrict__ ent,   // (N_ENT, 128)
                  const float* __restrict__ rel,   // (64, 128)
                  const float* __restrict__ W,     // (64, 128, 128)
                  float* __restrict__ per_sample,  // (M,)
                  int M)
{
    int m = blockIdx.x;
    if (m >= M) return;
    int t = threadIdx.x;  // 0..127

    __shared__ float sh[E_DIM], sp[E_DIM], sn[E_DIM];
    __shared__ float wpart[3][2];  // per-wave partials for 3 reductions

    int hi = h_idx[m];
    int ri = r_idx[m];
    int pi = pt_idx[m];
    int ni = nt_idx[m];

    float he = ent[(size_t)hi * E_DIM + t];
    float pe = ent[(size_t)pi * E_DIM + t];
    float ne = ent[(size_t)ni * E_DIM + t];
    float re = rel[(size_t)ri * R_DIM + t];

    sh[t] = he; sp[t] = pe; sn[t] = ne;
    __syncthreads();

    const float* Wr = W + (size_t)ri * (E_DIM * R_DIM);

    float ah = 0.f, ap = 0.f, an = 0.f;
#pragma unroll 8
    for (int e = 0; e < E_DIM; ++e) {
        float w = Wr[e * R_DIM + t];  // coalesced across t
        ah = fmaf(sh[e], w, ah);
        ap = fmaf(sp[e], w, ap);
        an = fmaf(sn[e], w, an);
    }

    float a  = ah + re;        // h_vec + r_embed  (column t)
    float dp = a - ap;         // - pos_t_vec
    float dn = a - an;         // - neg_t_vec

    float pos = dp * dp;
    float neg = dn * dn;
    float reg = he * he + re * re + pe * pe + ne * ne;

    // wave64 shuffle reduce
#pragma unroll
    for (int off = 32; off > 0; off >>= 1) {
        pos += __shfl_down(pos, off);
        neg += __shfl_down(neg, off);
        reg += __shfl_down(reg, off);
    }
    int wave = t >> 6;
    if ((t & 63) == 0) { wpart[0][wave] = pos; wpart[1][wave] = neg; wpart[2][wave] = reg; }
    __syncthreads();

    if (t == 0) {
        float P = wpart[0][0] + wpart[0][1];
        float N = wpart[1][0] + wpart[1][1];
        float R = wpart[2][0] + wpart[2][1];
        float diff = 0.5f * (P - N);           // pos_score - neg_score
        // -log_sigmoid(diff) = softplus(-diff), numerically stable
        float z = -diff;
        float sp_v = fmaxf(z, 0.f) + log1pf(expf(-fabsf(z)));
        per_sample[m] = sp_v + REG_LAMBDA * 0.5f * R;
    }
}

// Single-block final reduction -> mean
__global__ void __launch_bounds__(256)
kge_reduce_kernel(const float* __restrict__ per_sample, float* __restrict__ out, int M)
{
    int t = threadIdx.x;
    float s = 0.f;
    for (int i = t; i < M; i += 256) s += per_sample[i];
#pragma unroll
    for (int off = 32; off > 0; off >>= 1) s += __shfl_down(s, off);
    __shared__ float part[4];
    if ((t & 63) == 0) part[t >> 6] = s;
    __syncthreads();
    if (t == 0) out[0] = (part[0] + part[1] + part[2] + part[3]) / (float)M;
}

extern "C" void kernel_launch(void* const* d_in, const int* in_sizes, int n_in,
                              void* d_out, int out_size, void* d_ws, size_t ws_size,
                              hipStream_t stream)
{
    const int*   h_idx  = (const int*)d_in[0];
    const int*   r_idx  = (const int*)d_in[1];
    const int*   pt_idx = (const int*)d_in[2];
    const int*   nt_idx = (const int*)d_in[3];
    const float* ent    = (const float*)d_in[4];
    const float* rel    = (const float*)d_in[5];
    const float* W      = (const float*)d_in[6];
    float* out = (float*)d_out;

    int M = in_sizes[0];
    float* per_sample = (float*)d_ws;  // M floats

    kge_sample_kernel<<<M, 128, 0, stream>>>(h_idx, r_idx, pt_idx, nt_idx,
                                             ent, rel, W, per_sample, M);
    kge_reduce_kernel<<<1, 256, 0, stream>>>(per_sample, out, M);
}